// Round 7
// baseline (411.295 us; speedup 1.0000x reference)
//
#include <hip/hip_runtime.h>
#include <math.h>

#define N_RADIAL 8
#define N_PSEUDO 4
#define EMB_DIM 32
#define CUTOFF 5.0f
#define WIDTH 0.5f
#define SQRT3_4PI 0.48860251190291992f   /* sqrt(3/(4*pi)) */
#define INV_SQRT2 0.70710678118654752f
#define PI_F 3.14159265358979323846f

#define SLICE_CAP 2500     /* atoms per slice: 2500*6*4B = 60KB static LDS */
#define MAX_BPS 25         /* blocks (chunks) per slice; partials = bps*A*24B */

// ---------------------------------------------------------------------------
// G[tc][tn][n][k] = sum_q W_species[tn,q] * Emb[tc, n*4+q] * Wc[n*4+q, k]
// for k = 0,1 only (v[:,:,2] is discarded by the reference).
// ---------------------------------------------------------------------------
__global__ void build_G_kernel(const float* __restrict__ W_species, // (4,4)
                               const float* __restrict__ Emb,       // (4,32)
                               const float* __restrict__ Wc,        // (32,3)
                               float* __restrict__ G) {
    int i = threadIdx.x;            // 256 threads, one per table entry
    int k  = i & 1;
    int n  = (i >> 1) & 7;
    int tn = (i >> 4) & 3;
    int tc = i >> 6;
    float acc = 0.0f;
    #pragma unroll
    for (int q = 0; q < N_PSEUDO; ++q) {
        int d = n * N_PSEUDO + q;
        acc += W_species[tn * N_PSEUDO + q] * Emb[tc * EMB_DIM + d] * Wc[d * 3 + k];
    }
    G[i] = acc;
}

// ---------------------------------------------------------------------------
// Phase 1: block (slice, chunk) scans its edge chunk, accumulates edges whose
// center lies in its atom slice into an LDS accumulator (f32 LDS atomics),
// then streams the 60KB partial to global. NO global atomics.
// ---------------------------------------------------------------------------
__global__ __launch_bounds__(256, 2)
void edge_slice_kernel(const float* __restrict__ vecs,      // (E,3)
                       const int*   __restrict__ centers,   // (E,)
                       const int*   __restrict__ neighbors, // (E,)
                       const int*   __restrict__ species,   // (A,)
                       const float* __restrict__ G,         // (4,4,8,2)
                       float*       __restrict__ partials,  // (bps, A, 6)
                       int E, int A, int nslice, int sliceSz, int chunkSz) {
    __shared__ float Gs[256];
    __shared__ float acc[SLICE_CAP * 6];

    const int slice   = blockIdx.x % nslice;
    const int chunk   = blockIdx.x / nslice;
    const int sliceLo = slice * sliceSz;
    const int sliceN  = min(sliceSz, A - sliceLo);   // last slice may be short

    if (threadIdx.x < 256) Gs[threadIdx.x] = G[threadIdx.x];
    for (int i = threadIdx.x; i < sliceN * 6; i += blockDim.x) acc[i] = 0.0f;
    __syncthreads();

    if (sliceN > 0) {
        const int beg = chunk * chunkSz;
        const int end = min(beg + chunkSz, E);
        for (int e = beg + (int)threadIdx.x; e < end; e += (int)blockDim.x) {
            int c = centers[e];
            unsigned local = (unsigned)(c - sliceLo);
            if (local >= (unsigned)sliceN) continue;   // not my slice

            float vx = vecs[3 * e + 0];
            float vy = vecs[3 * e + 1];
            float vz = vecs[3 * e + 2];
            float r  = sqrtf(vx * vx + vy * vy + vz * vz);
            if (r >= CUTOFF) continue;                 // fcut == 0 exactly

            int tc = species[c];
            int tn = species[neighbors[e]];

            float rinv = 1.0f / (r + 1e-10f);

            // ShiftedCosine cutoff
            float t = (r - (CUTOFF - WIDTH)) / WIDTH;
            t = fminf(fmaxf(t, 0.0f), 1.0f);
            float fcut = 0.5f * (1.0f + cosf(PI_F * t));

            // R[n] = sin((pi/CUTOFF)*r*(n+1)) via Chebyshev recurrence.
            float theta = (PI_F / CUTOFF) * r;
            float s1, c1;
            sincosf(theta, &s1, &c1);
            float twoc  = 2.0f * c1;
            float sn_m1 = 0.0f;
            float sn    = s1;

            const float* Gp = &Gs[((tc * 4 + tn) * 8) * 2];  // 16 floats
            float s0 = 0.0f, s1a = 0.0f;
            #pragma unroll
            for (int n = 0; n < N_RADIAL; ++n) {
                s0  = fmaf(sn, Gp[n * 2 + 0], s0);
                s1a = fmaf(sn, Gp[n * 2 + 1], s1a);
                float nxt = twoc * sn - sn_m1;
                sn_m1 = sn;
                sn = nxt;
            }
            float coef = rinv * fcut;
            s0 *= coef; s1a *= coef;

            // Y (m = -1,0,1) = (y, z, x)/r * sqrt(3/4pi)
            float Y0 = SQRT3_4PI * vy * rinv;
            float Y1 = SQRT3_4PI * vz * rinv;
            float Y2 = SQRT3_4PI * vx * rinv;

            float* a = &acc[local * 6];
            atomicAdd(a + 0, Y0 * s0);
            atomicAdd(a + 1, Y0 * s1a);
            atomicAdd(a + 2, Y1 * s0);
            atomicAdd(a + 3, Y1 * s1a);
            atomicAdd(a + 4, Y2 * s0);
            atomicAdd(a + 5, Y2 * s1a);
        }
    }
    __syncthreads();

    // Stream partial to global (coalesced).
    float* dst = partials + ((size_t)chunk * A + sliceLo) * 6;
    for (int i = threadIdx.x; i < sliceN * 6; i += blockDim.x) dst[i] = acc[i];
}

// ---------------------------------------------------------------------------
// Merge: per atom, sum the bps partials, then
// out[a][m][k]: k=0 -> v0[m], k=1 -> v1[m], k=2 -> cross(v0,v1)/sqrt2.
// ---------------------------------------------------------------------------
__global__ void merge_kernel(const float* __restrict__ partials, // (bps, A, 6)
                             float* __restrict__ out,            // (A,3,3)
                             int A, int bps) {
    int a = blockIdx.x * blockDim.x + threadIdx.x;
    if (a >= A) return;

    float v[6] = {0, 0, 0, 0, 0, 0};
    for (int c = 0; c < bps; ++c) {
        const float* p = partials + ((size_t)c * A + a) * 6;
        #pragma unroll
        for (int j = 0; j < 6; ++j) v[j] += p[j];
    }

    float a0 = v[0], b0 = v[1];   // m=0 (y)
    float a1 = v[2], b1 = v[3];   // m=1 (z)
    float a2 = v[4], b2 = v[5];   // m=2 (x)

    float c0 = (a1 * b2 - a2 * b1) * INV_SQRT2;
    float c1 = (a2 * b0 - a0 * b2) * INV_SQRT2;
    float c2 = (a0 * b1 - a1 * b0) * INV_SQRT2;

    float* o = out + (size_t)a * 9;
    o[0] = a0; o[1] = b0; o[2] = c0;
    o[3] = a1; o[4] = b1; o[5] = c1;
    o[6] = a2; o[7] = b2; o[8] = c2;
}

extern "C" void kernel_launch(void* const* d_in, const int* in_sizes, int n_in,
                              void* d_out, int out_size, void* d_ws, size_t ws_size,
                              hipStream_t stream) {
    const float* vecs      = (const float*)d_in[0];
    const float* W_species = (const float*)d_in[1];
    const float* Emb       = (const float*)d_in[2];
    const float* Wc        = (const float*)d_in[3];
    const int*   centers   = (const int*)d_in[4];
    const int*   neighbors = (const int*)d_in[5];
    const int*   species   = (const int*)d_in[6];

    int E = in_sizes[0] / 3;
    int A = in_sizes[6];

    int nslice  = (A + SLICE_CAP - 1) / SLICE_CAP;   // 20 for A=50k
    int sliceSz = (A + nslice - 1) / nslice;         // <= SLICE_CAP

    // Workspace: partials (bps, A, 6) f32 + 256-float G table.
    size_t perChunk = (size_t)A * 6 * sizeof(float);
    size_t budget   = (ws_size > 4096) ? ws_size - 4096 : 0;
    int bps = (int)(budget / perChunk);
    if (bps > MAX_BPS) bps = MAX_BPS;
    if (bps < 1) bps = 1;
    int chunkSz = (E + bps - 1) / bps;

    float* partials = (float*)d_ws;                      // (bps, A, 6)
    float* G        = partials + (size_t)bps * A * 6;    // 256 floats

    build_G_kernel<<<1, 256, 0, stream>>>(W_species, Emb, Wc, G);

    int grid = nslice * bps;
    edge_slice_kernel<<<grid, 256, 0, stream>>>(vecs, centers, neighbors,
                                                species, G, partials,
                                                E, A, nslice, sliceSz, chunkSz);

    const int threads = 256;
    int ablocks = (A + threads - 1) / threads;
    merge_kernel<<<ablocks, threads, 0, stream>>>(partials, (float*)d_out, A, bps);
}

// Round 8
// 193.934 us; speedup vs baseline: 2.1208x; 2.1208x over previous
//
#include <hip/hip_runtime.h>
#include <math.h>

#define N_RADIAL 8
#define N_PSEUDO 4
#define EMB_DIM 32
#define CUTOFF 5.0f
#define WIDTH 0.5f
#define SQRT3_4PI 0.48860251190291992f   /* sqrt(3/(4*pi)) */
#define INV_SQRT2 0.70710678118654752f
#define PI_F 3.14159265358979323846f

#define SLICE_SHIFT 7
#define SLICE_SZ 128            /* atoms per slice (power of 2) */
#define MAX_NSLICE 2048         /* LDS histogram capacity */
#define EPB 4096                /* edges per block in hist/scatter passes */

// ---------------------------------------------------------------------------
// G[tc][tn][n][k], k=0,1 only (v[:,:,2] is discarded by the reference).
// ---------------------------------------------------------------------------
__global__ void build_G_kernel(const float* __restrict__ W_species, // (4,4)
                               const float* __restrict__ Emb,       // (4,32)
                               const float* __restrict__ Wc,        // (32,3)
                               float* __restrict__ G) {
    int i = threadIdx.x;            // 256 threads, one per table entry
    int k  = i & 1;
    int n  = (i >> 1) & 7;
    int tn = (i >> 4) & 3;
    int tc = i >> 6;
    float acc = 0.0f;
    #pragma unroll
    for (int q = 0; q < N_PSEUDO; ++q) {
        int d = n * N_PSEUDO + q;
        acc += W_species[tn * N_PSEUDO + q] * Emb[tc * EMB_DIM + d] * Wc[d * 3 + k];
    }
    G[i] = acc;
}

// ---------------------------------------------------------------------------
// Shared per-edge math. Returns false if the edge is cut off.
// Products out: pr[j] = Y[m]*s[k] packed (m-major): (Y0s0,Y0s1,Y1s0,Y1s1,Y2s0,Y2s1)
// ---------------------------------------------------------------------------
__device__ __forceinline__ bool edge_products(float vx, float vy, float vz,
                                              const float* __restrict__ Gp,
                                              float pr[6]) {
    float r = sqrtf(vx * vx + vy * vy + vz * vz);
    if (r >= CUTOFF) return false;

    float rinv = 1.0f / (r + 1e-10f);

    float t = (r - (CUTOFF - WIDTH)) / WIDTH;
    t = fminf(fmaxf(t, 0.0f), 1.0f);
    float fcut = 0.5f * (1.0f + cosf(PI_F * t));

    float theta = (PI_F / CUTOFF) * r;
    float s1, c1;
    sincosf(theta, &s1, &c1);
    float twoc  = 2.0f * c1;
    float sn_m1 = 0.0f;
    float sn    = s1;

    float s0 = 0.0f, s1a = 0.0f;
    #pragma unroll
    for (int n = 0; n < N_RADIAL; ++n) {
        s0  = fmaf(sn, Gp[n * 2 + 0], s0);
        s1a = fmaf(sn, Gp[n * 2 + 1], s1a);
        float nxt = twoc * sn - sn_m1;
        sn_m1 = sn;
        sn = nxt;
    }
    float coef = rinv * fcut;
    s0 *= coef; s1a *= coef;

    float Y0 = SQRT3_4PI * vy * rinv;
    float Y1 = SQRT3_4PI * vz * rinv;
    float Y2 = SQRT3_4PI * vx * rinv;

    pr[0] = Y0 * s0; pr[1] = Y0 * s1a;
    pr[2] = Y1 * s0; pr[3] = Y1 * s1a;
    pr[4] = Y2 * s0; pr[5] = Y2 * s1a;
    return true;
}

// ---------------------------------------------------------------------------
// Pass 1: per-block LDS histogram of passing edges per slice, flushed with
// one global u32 atomic per touched slice (~nslice per block, tiny).
// ---------------------------------------------------------------------------
__global__ __launch_bounds__(256)
void hist_kernel(const float* __restrict__ vecs, const int* __restrict__ centers,
                 unsigned int* __restrict__ ghist, int E, int nslice) {
    __shared__ unsigned int hist[MAX_NSLICE];
    for (int i = threadIdx.x; i < nslice; i += blockDim.x) hist[i] = 0u;
    __syncthreads();

    int beg = blockIdx.x * EPB;
    int end = min(beg + EPB, E);
    for (int e = beg + (int)threadIdx.x; e < end; e += (int)blockDim.x) {
        float vx = vecs[3 * e + 0], vy = vecs[3 * e + 1], vz = vecs[3 * e + 2];
        float r = sqrtf(vx * vx + vy * vy + vz * vz);
        if (r >= CUTOFF) continue;
        atomicAdd(&hist[centers[e] >> SLICE_SHIFT], 1u);
    }
    __syncthreads();

    for (int i = threadIdx.x; i < nslice; i += blockDim.x)
        if (hist[i]) atomicAdd(&ghist[i], hist[i]);
}

// ---------------------------------------------------------------------------
// Pass 2: serial exclusive scan (nslice <= 2048, trivial) -> sliceStart,
// and cursor init.
// ---------------------------------------------------------------------------
__global__ void scan_kernel(const unsigned int* __restrict__ ghist,
                            unsigned int* __restrict__ sliceStart,
                            unsigned int* __restrict__ cursor, int nslice) {
    if (threadIdx.x == 0) {
        unsigned int run = 0;
        for (int s = 0; s < nslice; ++s) {
            sliceStart[s] = run;
            cursor[s] = run;
            run += ghist[s];
        }
        sliceStart[nslice] = run;
    }
}

// ---------------------------------------------------------------------------
// Pass 3: re-count locally, reserve contiguous ranges per (block, slice) with
// one global atomic each, then compute dense per-edge math and scatter 32B
// payloads [lid, pr0..pr5, 0] into slice-sorted order.
// ---------------------------------------------------------------------------
__global__ __launch_bounds__(256)
void scatter_kernel(const float* __restrict__ vecs,
                    const int*   __restrict__ centers,
                    const int*   __restrict__ neighbors,
                    const int*   __restrict__ species,
                    const float* __restrict__ G,
                    unsigned int* __restrict__ cursor,
                    float4*      __restrict__ payload,   // 2 float4 per entry
                    int E, int nslice) {
    __shared__ float Gs[256];
    __shared__ unsigned int hist[MAX_NSLICE];

    Gs[threadIdx.x] = G[threadIdx.x];
    for (int i = threadIdx.x; i < nslice; i += blockDim.x) hist[i] = 0u;
    __syncthreads();

    int beg = blockIdx.x * EPB;
    int end = min(beg + EPB, E);

    // local count (must use the identical pass predicate as below)
    for (int e = beg + (int)threadIdx.x; e < end; e += (int)blockDim.x) {
        float vx = vecs[3 * e + 0], vy = vecs[3 * e + 1], vz = vecs[3 * e + 2];
        float r = sqrtf(vx * vx + vy * vy + vz * vz);
        if (r >= CUTOFF) continue;
        atomicAdd(&hist[centers[e] >> SLICE_SHIFT], 1u);
    }
    __syncthreads();

    // reserve global ranges; hist[s] becomes this block's running cursor
    for (int s = threadIdx.x; s < nslice; s += (int)blockDim.x) {
        unsigned int c = hist[s];
        hist[s] = c ? atomicAdd(&cursor[s], c) : 0u;
    }
    __syncthreads();

    // dense math + placement
    for (int e = beg + (int)threadIdx.x; e < end; e += (int)blockDim.x) {
        float vx = vecs[3 * e + 0], vy = vecs[3 * e + 1], vz = vecs[3 * e + 2];
        int c = centers[e];
        int slice = c >> SLICE_SHIFT;
        int tc = species[c];
        int tn = species[neighbors[e]];
        const float* Gp = &Gs[((tc * 4 + tn) * 8) * 2];

        float pr[6];
        if (!edge_products(vx, vy, vz, Gp, pr)) continue;

        unsigned int pos = atomicAdd(&hist[slice], 1u);
        unsigned int lid = (unsigned int)(c & (SLICE_SZ - 1));
        payload[2 * (size_t)pos + 0] = make_float4(__uint_as_float(lid), pr[0], pr[1], pr[2]);
        payload[2 * (size_t)pos + 1] = make_float4(pr[3], pr[4], pr[5], 0.0f);
    }
}

// ---------------------------------------------------------------------------
// Pass 4: one block per slice. Contiguous payload reads, LDS f32 atomics
// (stride 9 => gcd(9,32)=1, <=2-way bank aliasing), cross-product epilogue,
// direct output write. Zero global atomics.
// ---------------------------------------------------------------------------
__global__ __launch_bounds__(256)
void accum_kernel(const float4* __restrict__ payload,
                  const unsigned int* __restrict__ sliceStart,
                  float* __restrict__ out, int A) {
    __shared__ float acc[SLICE_SZ * 9];
    int s = blockIdx.x;

    for (int i = threadIdx.x; i < SLICE_SZ * 9; i += blockDim.x) acc[i] = 0.0f;
    __syncthreads();

    unsigned int beg = sliceStart[s], end = sliceStart[s + 1];
    for (unsigned int i = beg + threadIdx.x; i < end; i += blockDim.x) {
        float4 pl0 = payload[2 * (size_t)i + 0];
        float4 pl1 = payload[2 * (size_t)i + 1];
        int lid = (int)__float_as_uint(pl0.x);
        float* ap = &acc[lid * 9];
        atomicAdd(ap + 0, pl0.y);
        atomicAdd(ap + 1, pl0.z);
        atomicAdd(ap + 2, pl0.w);
        atomicAdd(ap + 3, pl1.x);
        atomicAdd(ap + 4, pl1.y);
        atomicAdd(ap + 5, pl1.z);
    }
    __syncthreads();

    int a = s * SLICE_SZ + (int)threadIdx.x;
    if (threadIdx.x < SLICE_SZ && a < A) {
        const float* v = &acc[threadIdx.x * 9];
        float a0 = v[0], b0 = v[1];   // m=0 (y)
        float a1 = v[2], b1 = v[3];   // m=1 (z)
        float a2 = v[4], b2 = v[5];   // m=2 (x)

        float c0 = (a1 * b2 - a2 * b1) * INV_SQRT2;
        float c1 = (a2 * b0 - a0 * b2) * INV_SQRT2;
        float c2 = (a0 * b1 - a1 * b0) * INV_SQRT2;

        float* o = out + (size_t)a * 9;
        o[0] = a0; o[1] = b0; o[2] = c0;
        o[3] = a1; o[4] = b1; o[5] = c1;
        o[6] = a2; o[7] = b2; o[8] = c2;
    }
}

// ===========================================================================
// Fallback path (Round 6): packed fixed-point u64 global atomics. Used only
// if the workspace can't hold the sort payload.
// ===========================================================================
#define Q_INV 8192.0f
#define Q 1.220703125e-4
#define BIAS_ENC 131072.0f
#define ENC_MAX 262143.0f
#define FIELD_MASK 0x3FFFFFFULL

__global__ void edge_kernel_fb(const float* __restrict__ vecs,
                               const int* __restrict__ centers,
                               const int* __restrict__ neighbors,
                               const int* __restrict__ species,
                               const float* __restrict__ G,
                               unsigned long long* __restrict__ vacc, int E) {
    __shared__ float Gs[256];
    Gs[threadIdx.x] = G[threadIdx.x];
    __syncthreads();

    int e = blockIdx.x * blockDim.x + threadIdx.x;
    if (e >= E) return;

    float vx = vecs[3 * e + 0], vy = vecs[3 * e + 1], vz = vecs[3 * e + 2];
    int c = centers[e];
    int tc = species[c];
    int tn = species[neighbors[e]];
    const float* Gp = &Gs[((tc * 4 + tn) * 8) * 2];

    float pr[6];
    if (!edge_products(vx, vy, vz, Gp, pr)) return;

    unsigned long long* base = vacc + (size_t)c * 4;
    #pragma unroll
    for (int j = 0; j < 3; ++j) {
        float el = fminf(fmaxf(fmaf(pr[2 * j + 0], Q_INV, BIAS_ENC) + 0.5f, 0.0f), ENC_MAX);
        float eh = fminf(fmaxf(fmaf(pr[2 * j + 1], Q_INV, BIAS_ENC) + 0.5f, 0.0f), ENC_MAX);
        unsigned long long w = (1ULL << 52)
                             | ((unsigned long long)(unsigned int)eh << 26)
                             | (unsigned long long)(unsigned int)el;
        atomicAdd(base + j, w);
    }
}

__global__ void finalize_fb(const unsigned long long* __restrict__ vacc,
                            float* __restrict__ out, int A) {
    int a = blockIdx.x * blockDim.x + threadIdx.x;
    if (a >= A) return;

    const unsigned long long* w = vacc + (size_t)a * 4;
    double v[6];
    #pragma unroll
    for (int j = 0; j < 3; ++j) {
        unsigned long long x = w[j];
        double n = (double)(x >> 52);
        v[2 * j + 0] = (double)(x & FIELD_MASK)         * (double)Q - n * 16.0;
        v[2 * j + 1] = (double)((x >> 26) & FIELD_MASK) * (double)Q - n * 16.0;
    }
    float a0 = (float)v[0], b0 = (float)v[1];
    float a1 = (float)v[2], b1 = (float)v[3];
    float a2 = (float)v[4], b2 = (float)v[5];
    float c0 = (a1 * b2 - a2 * b1) * INV_SQRT2;
    float c1 = (a2 * b0 - a0 * b2) * INV_SQRT2;
    float c2 = (a0 * b1 - a1 * b0) * INV_SQRT2;
    float* o = out + (size_t)a * 9;
    o[0] = a0; o[1] = b0; o[2] = c0;
    o[3] = a1; o[4] = b1; o[5] = c1;
    o[6] = a2; o[7] = b2; o[8] = c2;
}

extern "C" void kernel_launch(void* const* d_in, const int* in_sizes, int n_in,
                              void* d_out, int out_size, void* d_ws, size_t ws_size,
                              hipStream_t stream) {
    const float* vecs      = (const float*)d_in[0];
    const float* W_species = (const float*)d_in[1];
    const float* Emb       = (const float*)d_in[2];
    const float* Wc        = (const float*)d_in[3];
    const int*   centers   = (const int*)d_in[4];
    const int*   neighbors = (const int*)d_in[5];
    const int*   species   = (const int*)d_in[6];

    int E = in_sizes[0] / 3;
    int A = in_sizes[6];

    int nslice = (A + SLICE_SZ - 1) / SLICE_SZ;

    // Workspace layout (sort path): payload | ghist | sliceStart | cursor | G
    size_t payloadBytes = (size_t)E * 8 * sizeof(float);
    size_t metaBytes    = (size_t)(3 * nslice + 1 + 256) * sizeof(float) + 256;
    bool sort_path = (nslice <= MAX_NSLICE) && (ws_size >= payloadBytes + metaBytes);

    if (sort_path) {
        float4*       payload    = (float4*)d_ws;
        unsigned int* ghist      = (unsigned int*)((char*)d_ws + payloadBytes);
        unsigned int* sliceStart = ghist + nslice;
        unsigned int* cursor     = sliceStart + (nslice + 1);
        float*        G          = (float*)(cursor + nslice);

        (void)hipMemsetAsync(ghist, 0, (size_t)nslice * sizeof(unsigned int), stream);
        build_G_kernel<<<1, 256, 0, stream>>>(W_species, Emb, Wc, G);

        int nb = (E + EPB - 1) / EPB;
        hist_kernel<<<nb, 256, 0, stream>>>(vecs, centers, ghist, E, nslice);
        scan_kernel<<<1, 64, 0, stream>>>(ghist, sliceStart, cursor, nslice);
        scatter_kernel<<<nb, 256, 0, stream>>>(vecs, centers, neighbors, species,
                                               G, cursor, payload, E, nslice);
        accum_kernel<<<nslice, 256, 0, stream>>>(payload, sliceStart,
                                                 (float*)d_out, A);
    } else {
        unsigned long long* vacc = (unsigned long long*)d_ws;  // (A,4)
        float* G = (float*)(vacc + (size_t)A * 4);
        (void)hipMemsetAsync(vacc, 0, (size_t)A * 4 * sizeof(unsigned long long), stream);
        build_G_kernel<<<1, 256, 0, stream>>>(W_species, Emb, Wc, G);
        const int threads = 256;
        edge_kernel_fb<<<(E + threads - 1) / threads, threads, 0, stream>>>(
            vecs, centers, neighbors, species, G, vacc, E);
        finalize_fb<<<(A + threads - 1) / threads, threads, 0, stream>>>(
            vacc, (float*)d_out, A);
    }
}